// Round 1
// baseline (573.333 us; speedup 1.0000x reference)
//
#include <hip/hip_runtime.h>
#include <stdint.h>
#include <math.h>

typedef unsigned short ushort_t;
typedef __attribute__((ext_vector_type(8))) short bf16x8;
typedef __attribute__((ext_vector_type(4))) float f32x4;

// round-to-nearest-even fp32 -> bf16 (no NaN special-casing needed for this data)
__device__ __forceinline__ ushort_t f2bf(float f) {
  union { float f; unsigned u; } cv; cv.f = f;
  unsigned r = cv.u + 0x7fffu + ((cv.u >> 16) & 1u);
  return (ushort_t)(r >> 16);
}

__device__ __forceinline__ void gl_lds16(const void* g, void* l) {
  typedef __attribute__((address_space(1))) const char gchar;
  typedef __attribute__((address_space(3))) char lchar;
  __builtin_amdgcn_global_load_lds((gchar*)g, (lchar*)l, 16, 0, 0);
}

// ---------------- LayerNorm (fp32 in) -> bf16 xn ----------------
__global__ __launch_bounds__(256) void ln_kernel(const float* __restrict__ x,
                                                 const float* __restrict__ gamma,
                                                 const float* __restrict__ beta,
                                                 ushort_t* __restrict__ xn) {
  const int row = blockIdx.x;
  const int t = threadIdx.x;
  const float4 v = ((const float4*)(x + (size_t)row * 1024))[t];
  float s  = v.x + v.y + v.z + v.w;
  float ss = v.x * v.x + v.y * v.y + v.z * v.z + v.w * v.w;
#pragma unroll
  for (int o = 32; o >= 1; o >>= 1) {
    s  += __shfl_xor(s, o);
    ss += __shfl_xor(ss, o);
  }
  __shared__ float red[10];
  const int wave = t >> 6, lane = t & 63;
  if (lane == 0) { red[wave] = s; red[4 + wave] = ss; }
  __syncthreads();
  if (t == 0) {
    float S  = red[0] + red[1] + red[2] + red[3];
    float SS = red[4] + red[5] + red[6] + red[7];
    float mu  = S * (1.0f / 1024.0f);
    float var = SS * (1.0f / 1024.0f) - mu * mu;
    red[8] = mu;
    red[9] = rsqrtf(var + 1e-5f);
  }
  __syncthreads();
  const float mu = red[8], rs = red[9];
  const float4 g = ((const float4*)gamma)[t];
  const float4 b = ((const float4*)beta)[t];
  ushort4 o;
  o.x = f2bf((v.x - mu) * rs * g.x + b.x);
  o.y = f2bf((v.y - mu) * rs * g.y + b.y);
  o.z = f2bf((v.z - mu) * rs * g.z + b.z);
  o.w = f2bf((v.w - mu) * rs * g.w + b.w);
  ((ushort4*)(xn + (size_t)row * 1024))[t] = o;
}

// ---------------- transpose + cast: in[e][R][C] fp32 -> out[e][C][R] bf16 ----------------
__global__ __launch_bounds__(256) void transpose_cast(const float* __restrict__ in,
                                                      ushort_t* __restrict__ out,
                                                      int R, int C) {
  __shared__ float tile[32][33];
  const int e = blockIdx.z;
  const float* src = in + (size_t)e * R * C;
  ushort_t* dst = out + (size_t)e * R * C;
  const int c0 = blockIdx.x * 32, r0 = blockIdx.y * 32;
  const int tx = threadIdx.x, ty = threadIdx.y;
#pragma unroll
  for (int j = 0; j < 32; j += 8)
    tile[ty + j][tx] = src[(size_t)(r0 + ty + j) * C + c0 + tx];
  __syncthreads();
#pragma unroll
  for (int j = 0; j < 32; j += 8)
    dst[(size_t)(c0 + ty + j) * R + r0 + tx] = f2bf(tile[tx][ty + j]);
}

// ---------------- GEMM1: h = gelu(xn @ w1[e] + b1[e]), bf16 out ----------------
// A: xn [16384][1024] bf16 row-major; B: w1t[e] [4096][1024] (n-major, k-contig)
__global__ __launch_bounds__(256) void gemm1_kernel(const ushort_t* __restrict__ xn,
                                                    const ushort_t* __restrict__ w1t,
                                                    const float* __restrict__ b1,
                                                    ushort_t* __restrict__ h) {
  __shared__ ushort_t sA[128 * 32];
  __shared__ ushort_t sB[128 * 32];
  const int tid = threadIdx.x;
  const int wave = tid >> 6, lane = tid & 63;
  const int wr = wave >> 1, wc = wave & 1;
  const int row0 = blockIdx.y * 128;
  const int col0 = blockIdx.x * 128;
  const int e = (row0 >> 9) & 7;
  const ushort_t* gA = xn + (size_t)row0 * 1024;
  const ushort_t* gB = w1t + ((size_t)e * 4096 + col0) * 1024;

  const int sr = tid >> 2;           // staging row 0..63
  const int sk = (tid & 3) * 8;      // staging k element offset

  f32x4 acc[4][4] = {};
  for (int kt = 0; kt < 1024; kt += 32) {
    gl_lds16(gA + (size_t)sr * 1024 + kt + sk,        (char*)sA + wave * 1024);
    gl_lds16(gA + (size_t)(sr + 64) * 1024 + kt + sk, (char*)sA + 4096 + wave * 1024);
    gl_lds16(gB + (size_t)sr * 1024 + kt + sk,        (char*)sB + wave * 1024);
    gl_lds16(gB + (size_t)(sr + 64) * 1024 + kt + sk, (char*)sB + 4096 + wave * 1024);
    __syncthreads();
    bf16x8 a[4], b[4];
#pragma unroll
    for (int mi = 0; mi < 4; mi++)
      a[mi] = *(const bf16x8*)&sA[(wr * 64 + mi * 16 + (lane & 15)) * 32 + (lane >> 4) * 8];
#pragma unroll
    for (int ni = 0; ni < 4; ni++)
      b[ni] = *(const bf16x8*)&sB[(wc * 64 + ni * 16 + (lane & 15)) * 32 + (lane >> 4) * 8];
#pragma unroll
    for (int mi = 0; mi < 4; mi++)
#pragma unroll
      for (int ni = 0; ni < 4; ni++)
        acc[mi][ni] = __builtin_amdgcn_mfma_f32_16x16x32_bf16(a[mi], b[ni], acc[mi][ni], 0, 0, 0);
    __syncthreads();
  }
#pragma unroll
  for (int ni = 0; ni < 4; ni++) {
    const int n = col0 + wc * 64 + ni * 16 + (lane & 15);
    const float bias = b1[e * 4096 + n];
#pragma unroll
    for (int mi = 0; mi < 4; mi++) {
#pragma unroll
      for (int r = 0; r < 4; r++) {
        const int row = row0 + wr * 64 + mi * 16 + (lane >> 4) * 4 + r;
        float v = acc[mi][ni][r] + bias;
        v = 0.5f * v * (1.0f + erff(v * 0.70710678118654752f));
        h[(size_t)row * 4096 + n] = f2bf(v);
      }
    }
  }
}

// ---------------- GEMM2: out = x + h @ w2[e] + b2[e], fp32 out ----------------
// A: h [16384][4096] bf16; B: w2t[e] [1024][4096] (n-major, k-contig)
__global__ __launch_bounds__(256) void gemm2_kernel(const ushort_t* __restrict__ h,
                                                    const ushort_t* __restrict__ w2t,
                                                    const float* __restrict__ b2,
                                                    const float* __restrict__ x,
                                                    float* __restrict__ out) {
  __shared__ ushort_t sA[128 * 32];
  __shared__ ushort_t sB[128 * 32];
  const int tid = threadIdx.x;
  const int wave = tid >> 6, lane = tid & 63;
  const int wr = wave >> 1, wc = wave & 1;
  const int row0 = blockIdx.y * 128;
  const int col0 = blockIdx.x * 128;
  const int e = (row0 >> 9) & 7;
  const ushort_t* gA = h + (size_t)row0 * 4096;
  const ushort_t* gB = w2t + ((size_t)e * 1024 + col0) * 4096;

  const int sr = tid >> 2;
  const int sk = (tid & 3) * 8;

  f32x4 acc[4][4] = {};
  for (int kt = 0; kt < 4096; kt += 32) {
    gl_lds16(gA + (size_t)sr * 4096 + kt + sk,        (char*)sA + wave * 1024);
    gl_lds16(gA + (size_t)(sr + 64) * 4096 + kt + sk, (char*)sA + 4096 + wave * 1024);
    gl_lds16(gB + (size_t)sr * 4096 + kt + sk,        (char*)sB + wave * 1024);
    gl_lds16(gB + (size_t)(sr + 64) * 4096 + kt + sk, (char*)sB + 4096 + wave * 1024);
    __syncthreads();
    bf16x8 a[4], b[4];
#pragma unroll
    for (int mi = 0; mi < 4; mi++)
      a[mi] = *(const bf16x8*)&sA[(wr * 64 + mi * 16 + (lane & 15)) * 32 + (lane >> 4) * 8];
#pragma unroll
    for (int ni = 0; ni < 4; ni++)
      b[ni] = *(const bf16x8*)&sB[(wc * 64 + ni * 16 + (lane & 15)) * 32 + (lane >> 4) * 8];
#pragma unroll
    for (int mi = 0; mi < 4; mi++)
#pragma unroll
      for (int ni = 0; ni < 4; ni++)
        acc[mi][ni] = __builtin_amdgcn_mfma_f32_16x16x32_bf16(a[mi], b[ni], acc[mi][ni], 0, 0, 0);
    __syncthreads();
  }
#pragma unroll
  for (int ni = 0; ni < 4; ni++) {
    const int n = col0 + wc * 64 + ni * 16 + (lane & 15);
    const float bias = b2[e * 1024 + n];
#pragma unroll
    for (int mi = 0; mi < 4; mi++) {
#pragma unroll
      for (int r = 0; r < 4; r++) {
        const int row = row0 + wr * 64 + mi * 16 + (lane >> 4) * 4 + r;
        out[(size_t)row * 1024 + n] = x[(size_t)row * 1024 + n] + acc[mi][ni][r] + bias;
      }
    }
  }
}

extern "C" void kernel_launch(void* const* d_in, const int* in_sizes, int n_in,
                              void* d_out, int out_size, void* d_ws, size_t ws_size,
                              hipStream_t stream) {
  const float* x     = (const float*)d_in[0];
  const float* gamma = (const float*)d_in[1];
  const float* beta  = (const float*)d_in[2];
  // d_in[3] = gate_w : logits are discarded by the reference -> skip
  const float* w1    = (const float*)d_in[4];
  const float* b1    = (const float*)d_in[5];
  const float* w2    = (const float*)d_in[6];
  const float* b2    = (const float*)d_in[7];
  float* out = (float*)d_out;

  char* ws = (char*)d_ws;
  ushort_t* xn  = (ushort_t*)ws;                                   // 16384*1024*2 = 32MB
  ushort_t* w1t = (ushort_t*)(ws + 33554432);                      // 8*4096*1024*2 = 64MB
  ushort_t* w2t = (ushort_t*)(ws + 33554432 + 67108864);           // 64MB
  ushort_t* h   = (ushort_t*)(ws + 33554432 + 2 * 67108864);       // 16384*4096*2 = 128MB

  ln_kernel<<<16384, 256, 0, stream>>>(x, gamma, beta, xn);
  // w1: [E][D=1024][F=4096] -> w1t [E][F][D]
  transpose_cast<<<dim3(128, 32, 8), dim3(32, 8), 0, stream>>>(w1, w1t, 1024, 4096);
  // w2: [E][F=4096][D=1024] -> w2t [E][D][F]
  transpose_cast<<<dim3(32, 128, 8), dim3(32, 8), 0, stream>>>(w2, w2t, 4096, 1024);
  gemm1_kernel<<<dim3(32, 128), 256, 0, stream>>>(xn, w1t, b1, h);
  gemm2_kernel<<<dim3(8, 128), 256, 0, stream>>>(h, w2t, b2, x, out);
}

// Round 2
// 472.220 us; speedup vs baseline: 1.2141x; 1.2141x over previous
//
#include <hip/hip_runtime.h>
#include <stdint.h>
#include <math.h>

typedef unsigned short ushort_t;
typedef __attribute__((ext_vector_type(8))) short bf16x8;
typedef __attribute__((ext_vector_type(4))) float f32x4;

__device__ __forceinline__ ushort_t f2bf(float f) {
  union { float f; unsigned u; } cv; cv.f = f;
  unsigned r = cv.u + 0x7fffu + ((cv.u >> 16) & 1u);
  return (ushort_t)(r >> 16);
}

__device__ __forceinline__ void gl_lds16(const void* g, void* l) {
  typedef __attribute__((address_space(1))) const char gchar;
  typedef __attribute__((address_space(3))) char lchar;
  __builtin_amdgcn_global_load_lds((gchar*)g, (lchar*)l, 16, 0, 0);
}

// ---------------- LayerNorm (fp32 in) -> bf16 xn ----------------
__global__ __launch_bounds__(256) void ln_kernel(const float* __restrict__ x,
                                                 const float* __restrict__ gamma,
                                                 const float* __restrict__ beta,
                                                 ushort_t* __restrict__ xn) {
  const int row = blockIdx.x;
  const int t = threadIdx.x;
  const float4 v = ((const float4*)(x + (size_t)row * 1024))[t];
  float s  = v.x + v.y + v.z + v.w;
  float ss = v.x * v.x + v.y * v.y + v.z * v.z + v.w * v.w;
#pragma unroll
  for (int o = 32; o >= 1; o >>= 1) {
    s  += __shfl_xor(s, o);
    ss += __shfl_xor(ss, o);
  }
  __shared__ float red[10];
  const int wave = t >> 6, lane = t & 63;
  if (lane == 0) { red[wave] = s; red[4 + wave] = ss; }
  __syncthreads();
  if (t == 0) {
    float S  = red[0] + red[1] + red[2] + red[3];
    float SS = red[4] + red[5] + red[6] + red[7];
    float mu  = S * (1.0f / 1024.0f);
    float var = SS * (1.0f / 1024.0f) - mu * mu;
    red[8] = mu;
    red[9] = rsqrtf(var + 1e-5f);
  }
  __syncthreads();
  const float mu = red[8], rs = red[9];
  const float4 g = ((const float4*)gamma)[t];
  const float4 b = ((const float4*)beta)[t];
  ushort4 o;
  o.x = f2bf((v.x - mu) * rs * g.x + b.x);
  o.y = f2bf((v.y - mu) * rs * g.y + b.y);
  o.z = f2bf((v.z - mu) * rs * g.z + b.z);
  o.w = f2bf((v.w - mu) * rs * g.w + b.w);
  ((ushort4*)(xn + (size_t)row * 1024))[t] = o;
}

// ---------------- transpose + cast: in[e][R][C] fp32 -> out[e][C][R] bf16 ----------------
__global__ __launch_bounds__(256) void transpose_cast(const float* __restrict__ in,
                                                      ushort_t* __restrict__ out,
                                                      int R, int C) {
  __shared__ float tile[32][33];
  const int e = blockIdx.z;
  const float* src = in + (size_t)e * R * C;
  ushort_t* dst = out + (size_t)e * R * C;
  const int c0 = blockIdx.x * 32, r0 = blockIdx.y * 32;
  const int tx = threadIdx.x, ty = threadIdx.y;
#pragma unroll
  for (int j = 0; j < 32; j += 8)
    tile[ty + j][tx] = src[(size_t)(r0 + ty + j) * C + c0 + tx];
  __syncthreads();
#pragma unroll
  for (int j = 0; j < 32; j += 8)
    dst[(size_t)(c0 + ty + j) * R + r0 + tx] = f2bf(tile[tx][ty + j]);
}

// ================= 256x256 / BK=32 / ring-4 deep-pipelined GEMM =================
// LDS slot (32KB): A-h0 @0, A-h1 @8192, B-h0 @16384, B-h1 @24576
// half-tile = 128 rows x 32 k (64B rows); swizzle: byte ^= ((row&3)<<4)
#define SLOT_BYTES 32768

#define SYNC_V(N) do { \
  asm volatile("s_waitcnt vmcnt(" #N ") lgkmcnt(0)" ::: "memory"); \
  __builtin_amdgcn_s_barrier(); \
  asm volatile("" ::: "memory"); } while (0)

__device__ __forceinline__ void stage_tile(const ushort_t* gA, const ushort_t* gB,
                                           int lda, int ldb, char* slot, int kt,
                                           int tid, int wave) {
  const int rr = tid >> 2;                       // 0..127 (row within half)
  const int gs = (tid & 3) ^ (rr & 3);           // inverse-swizzled k-granule
  const int kc = kt + gs * 8;
  char* ldsw = slot + wave * 1024;               // wave-uniform; HW adds lane*16
  gl_lds16(gA + (size_t)rr * lda + kc,         ldsw);
  gl_lds16(gA + (size_t)(rr + 128) * lda + kc, ldsw + 8192);
  gl_lds16(gB + (size_t)rr * ldb + kc,         ldsw + 16384);
  gl_lds16(gB + (size_t)(rr + 128) * ldb + kc, ldsw + 24576);
}

__device__ __forceinline__ void compute_tile(const char* slot, int a_off, int b_off,
                                             f32x4 (&acc)[8][4]) {
  const char* sa = slot + a_off;
  const char* sb = slot + b_off;
  bf16x8 a[8], b[4];
#pragma unroll
  for (int ni = 0; ni < 4; ni++) b[ni] = *(const bf16x8*)(sb + ni * 1024);
#pragma unroll
  for (int mi = 0; mi < 4; mi++) a[mi] = *(const bf16x8*)(sa + mi * 1024);
  __builtin_amdgcn_s_setprio(1);
#pragma unroll
  for (int mi = 0; mi < 4; mi++)
#pragma unroll
    for (int ni = 0; ni < 4; ni++)
      acc[mi][ni] = __builtin_amdgcn_mfma_f32_16x16x32_bf16(a[mi], b[ni], acc[mi][ni], 0, 0, 0);
  __builtin_amdgcn_s_setprio(0);
#pragma unroll
  for (int mi = 4; mi < 8; mi++) a[mi] = *(const bf16x8*)(sa + mi * 1024);
  __builtin_amdgcn_s_setprio(1);
#pragma unroll
  for (int mi = 4; mi < 8; mi++)
#pragma unroll
    for (int ni = 0; ni < 4; ni++)
      acc[mi][ni] = __builtin_amdgcn_mfma_f32_16x16x32_bf16(a[mi], b[ni], acc[mi][ni], 0, 0, 0);
  __builtin_amdgcn_s_setprio(0);
}

// EPI=0: H = gelu(A@B + bias), bf16 out (ldc=LDC). EPI=1: O = resid + A@B + bias, f32.
template <int EPI, int LDA, int LDC, int KTOT>
__global__ __launch_bounds__(512, 2) void gemm256(const ushort_t* __restrict__ A,
                                                  const ushort_t* __restrict__ Bw,
                                                  const float* __restrict__ bias,
                                                  const float* __restrict__ resid,
                                                  ushort_t* __restrict__ Hout,
                                                  float* __restrict__ Fout) {
  extern __shared__ char smem[];
  const int tid = threadIdx.x;
  const int wave = tid >> 6, lane = tid & 63;

  // XCD-aware bijective swizzle; per XCD: 8 m-tiles x NTN n-tiles
  const int bid = blockIdx.x;
  const int c = bid & 7, l = bid >> 3;
  const int tm = c * 8 + (l & 7);
  const int tn = l >> 3;
  const int row0 = tm * 256;
  const int col0 = tn * 256;
  const int e = (row0 >> 9) & 7;

  const ushort_t* gA = A + (size_t)row0 * LDA;
  const ushort_t* gB = Bw + ((size_t)e * LDC + col0) * LDA;   // B panel [256 n][K]

  const int NT = KTOT / 32;

  // read offsets (swizzled)
  const int wm = wave >> 2, wn = wave & 3;
  const int l15 = lane & 15, g = lane >> 4;
  const int sw = ((g ^ (lane & 3)) << 4);
  const int a_off = wm * 8192 + l15 * 64 + sw;
  const int b_off = 16384 + (wn >> 1) * 8192 + (wn & 1) * 4096 + l15 * 64 + sw;

  f32x4 acc[8][4] = {};

  // prologue: stage tiles 0,1,2
  stage_tile(gA, gB, LDA, LDA, smem + 0 * SLOT_BYTES, 0,  tid, wave);
  stage_tile(gA, gB, LDA, LDA, smem + 1 * SLOT_BYTES, 32, tid, wave);
  stage_tile(gA, gB, LDA, LDA, smem + 2 * SLOT_BYTES, 64, tid, wave);

  for (int T = 0; T < NT - 2; ++T) {
    SYNC_V(8);                                    // tile T landed; prev reads done
    if (T + 3 < NT)
      stage_tile(gA, gB, LDA, LDA, smem + ((T + 3) & 3) * SLOT_BYTES, (T + 3) * 32, tid, wave);
    compute_tile(smem + (T & 3) * SLOT_BYTES, a_off, b_off, acc);
  }
  SYNC_V(4);
  compute_tile(smem + ((NT - 2) & 3) * SLOT_BYTES, a_off, b_off, acc);
  SYNC_V(0);
  compute_tile(smem + ((NT - 1) & 3) * SLOT_BYTES, a_off, b_off, acc);

  // ---------------- epilogue ----------------
  const int rbase = row0 + wm * 128 + g * 4;
  const int cbase = col0 + wn * 64 + l15;
  const float* bp = bias + e * LDC;
#pragma unroll
  for (int ni = 0; ni < 4; ni++) {
    const int n = cbase + ni * 16;
    const float bv = bp[n];
#pragma unroll
    for (int mi = 0; mi < 8; mi++) {
#pragma unroll
      for (int r = 0; r < 4; r++) {
        const int row = rbase + mi * 16 + r;
        float v = acc[mi][ni][r] + bv;
        if (EPI == 0) {
          // tanh-GELU: v * sigmoid(2*0.7978845608*(v + 0.044715 v^3))
          float v2 = v * v;
          float cc = fmaf(0.044715f, v2, 1.0f);
          float xa = -2.3022078f * v * cc;          // -2*k*log2(e)*v*cc
          float u  = exp2f(xa);
          float o  = __fdividef(v, 1.0f + u);
          Hout[(size_t)row * LDC + n] = (ushort_t)f2bf(o);
        } else {
          const size_t idx = (size_t)row * LDC + n;
          Fout[idx] = resid[idx] + v;
        }
      }
    }
  }
}

extern "C" void kernel_launch(void* const* d_in, const int* in_sizes, int n_in,
                              void* d_out, int out_size, void* d_ws, size_t ws_size,
                              hipStream_t stream) {
  const float* x     = (const float*)d_in[0];
  const float* gamma = (const float*)d_in[1];
  const float* beta  = (const float*)d_in[2];
  // d_in[3] = gate_w : logits discarded by the reference -> skip
  const float* w1    = (const float*)d_in[4];
  const float* b1    = (const float*)d_in[5];
  const float* w2    = (const float*)d_in[6];
  const float* b2    = (const float*)d_in[7];
  float* out = (float*)d_out;

  char* ws = (char*)d_ws;
  ushort_t* xn  = (ushort_t*)ws;                                   // 32MB
  ushort_t* w1t = (ushort_t*)(ws + 33554432);                      // 64MB
  ushort_t* w2t = (ushort_t*)(ws + 33554432 + 67108864);           // 64MB
  ushort_t* h   = (ushort_t*)(ws + 33554432 + 2 * 67108864);       // 128MB

  static bool attr_done = false;
  (void)attr_done;  // hipFuncSetAttribute is idempotent & host-side; safe under capture
  hipFuncSetAttribute(reinterpret_cast<const void*>(&gemm256<0, 1024, 4096, 1024>),
                      hipFuncAttributeMaxDynamicSharedMemorySize, 131072);
  hipFuncSetAttribute(reinterpret_cast<const void*>(&gemm256<1, 4096, 1024, 4096>),
                      hipFuncAttributeMaxDynamicSharedMemorySize, 131072);

  ln_kernel<<<16384, 256, 0, stream>>>(x, gamma, beta, xn);
  transpose_cast<<<dim3(128, 32, 8), dim3(32, 8), 0, stream>>>(w1, w1t, 1024, 4096);
  transpose_cast<<<dim3(32, 128, 8), dim3(32, 8), 0, stream>>>(w2, w2t, 4096, 1024);

  // GEMM1: M=16384 N=4096 K=1024 -> h = gelu(xn@w1 + b1)
  gemm256<0, 1024, 4096, 1024><<<dim3(1024), 512, 131072, stream>>>(xn, w1t, b1, nullptr, h, nullptr);
  // GEMM2: M=16384 N=1024 K=4096 -> out = x + h@w2 + b2
  gemm256<1, 4096, 1024, 4096><<<dim3(256), 512, 131072, stream>>>(h, w2t, b2, x, nullptr, out);
}

// Round 3
// 463.767 us; speedup vs baseline: 1.2363x; 1.0182x over previous
//
#include <hip/hip_runtime.h>
#include <stdint.h>
#include <math.h>

typedef unsigned short ushort_t;
typedef __attribute__((ext_vector_type(8))) short bf16x8;
typedef __attribute__((ext_vector_type(4))) float f32x4;

#define SLOT 32768

__device__ __forceinline__ ushort_t f2bf(float f) {
  union { float f; unsigned u; } cv; cv.f = f;
  unsigned r = cv.u + 0x7fffu + ((cv.u >> 16) & 1u);
  return (ushort_t)(r >> 16);
}

__device__ __forceinline__ void gl_lds16(const void* g, void* l) {
  typedef __attribute__((address_space(1))) const char gchar;
  typedef __attribute__((address_space(3))) char lchar;
  __builtin_amdgcn_global_load_lds((gchar*)g, (lchar*)l, 16, 0, 0);
}

__device__ __forceinline__ f32x4 MFMA(bf16x8 a, bf16x8 b, f32x4 c) {
  return __builtin_amdgcn_mfma_f32_16x16x32_bf16(a, b, c, 0, 0, 0);
}

// ---------------- LayerNorm (fp32 in) -> bf16 xn ----------------
__global__ __launch_bounds__(256) void ln_kernel(const float* __restrict__ x,
                                                 const float* __restrict__ gamma,
                                                 const float* __restrict__ beta,
                                                 ushort_t* __restrict__ xn) {
  const int row = blockIdx.x;
  const int t = threadIdx.x;
  const float4 v = ((const float4*)(x + (size_t)row * 1024))[t];
  float s  = v.x + v.y + v.z + v.w;
  float ss = v.x * v.x + v.y * v.y + v.z * v.z + v.w * v.w;
#pragma unroll
  for (int o = 32; o >= 1; o >>= 1) {
    s  += __shfl_xor(s, o);
    ss += __shfl_xor(ss, o);
  }
  __shared__ float red[10];
  const int wave = t >> 6, lane = t & 63;
  if (lane == 0) { red[wave] = s; red[4 + wave] = ss; }
  __syncthreads();
  if (t == 0) {
    float S  = red[0] + red[1] + red[2] + red[3];
    float SS = red[4] + red[5] + red[6] + red[7];
    float mu  = S * (1.0f / 1024.0f);
    float var = SS * (1.0f / 1024.0f) - mu * mu;
    red[8] = mu;
    red[9] = rsqrtf(var + 1e-5f);
  }
  __syncthreads();
  const float mu = red[8], rs = red[9];
  const float4 g = ((const float4*)gamma)[t];
  const float4 b = ((const float4*)beta)[t];
  ushort4 o;
  o.x = f2bf((v.x - mu) * rs * g.x + b.x);
  o.y = f2bf((v.y - mu) * rs * g.y + b.y);
  o.z = f2bf((v.z - mu) * rs * g.z + b.z);
  o.w = f2bf((v.w - mu) * rs * g.w + b.w);
  ((ushort4*)(xn + (size_t)row * 1024))[t] = o;
}

// ---------------- transpose + cast: in[e][R][C] fp32 -> out[e][C][R] bf16 ----------------
__global__ __launch_bounds__(256) void transpose_cast(const float* __restrict__ in,
                                                      ushort_t* __restrict__ out,
                                                      int R, int C) {
  __shared__ float tile[32][33];
  const int e = blockIdx.z;
  const float* src = in + (size_t)e * R * C;
  ushort_t* dst = out + (size_t)e * R * C;
  const int c0 = blockIdx.x * 32, r0 = blockIdx.y * 32;
  const int tx = threadIdx.x, ty = threadIdx.y;
#pragma unroll
  for (int j = 0; j < 32; j += 8)
    tile[ty + j][tx] = src[(size_t)(r0 + ty + j) * C + c0 + tx];
  __syncthreads();
#pragma unroll
  for (int j = 0; j < 32; j += 8)
    dst[(size_t)(c0 + ty + j) * R + r0 + tx] = f2bf(tile[tx][ty + j]);
}

// ================= 256x256 / BK=32 / ring-4, 2-phase-per-tile GEMM =================
// Slot (32KB): A-h0 @0, A-h1 @8192, B-h0 @16384, B-h1 @24576. Rows = 64B (4x16B granules).
// Swizzle: global granule g of row r lives at LDS slot g ^ ((r>>1)&3)  (2-way = free).

__device__ __forceinline__ void stage_half(const ushort_t* gsrc, int lda,
                                           char* half_base, int kt, int tid) {
  const int rr = tid >> 2;                          // 0..127 (row in half)
  const int gs = (tid & 3) ^ ((tid >> 3) & 3);      // inverse-swizzled source granule
  gl_lds16(gsrc + (size_t)rr * lda + kt + gs * 8, half_base + (tid >> 6) * 1024);
}

// VM: vmcnt immediate for this tile's phase-B wait (-1 = lgkm only). STG: stage tile T+3.
template <int VM, bool STG>
__device__ __forceinline__ void tile_body(char* smem, int T,
                                          const ushort_t* gA, const ushort_t* gB,
                                          int lda, int a_off, int b_off, int tid,
                                          f32x4 (&acc)[8][4]) {
  const char* slot = smem + (T & 3) * SLOT;
  char* nslot = smem + ((T + 3) & 3) * SLOT;
  const int kt3 = (T + 3) * 32;
  bf16x8 a[4], b[4];
  // ---- phase A: B-frags + A-frags mi0-3; stage A-halves of T+3 ----
#pragma unroll
  for (int ni = 0; ni < 4; ni++) b[ni] = *(const bf16x8*)(slot + b_off + ni * 1024);
#pragma unroll
  for (int mi = 0; mi < 4; mi++) a[mi] = *(const bf16x8*)(slot + a_off + mi * 1024);
  if (STG) {
    stage_half(gA, lda, nslot, kt3, tid);
    stage_half(gA + (size_t)128 * lda, lda, nslot + 8192, kt3, tid);
  }
  __builtin_amdgcn_s_barrier();
  asm volatile("s_waitcnt lgkmcnt(0)" ::: "memory");
  __builtin_amdgcn_s_setprio(1);
#pragma unroll
  for (int mi = 0; mi < 4; mi++)
#pragma unroll
    for (int ni = 0; ni < 4; ni++)
      acc[mi][ni] = MFMA(a[mi], b[ni], acc[mi][ni]);
  __builtin_amdgcn_s_setprio(0);
  __builtin_amdgcn_s_barrier();
  // ---- phase B: A-frags mi4-7; stage B-halves of T+3; counted vmcnt ----
#pragma unroll
  for (int mi = 0; mi < 4; mi++) a[mi] = *(const bf16x8*)(slot + a_off + (mi + 4) * 1024);
  if (STG) {
    stage_half(gB, lda, nslot + 16384, kt3, tid);
    stage_half(gB + (size_t)128 * lda, lda, nslot + 24576, kt3, tid);
  }
  if (VM == 8)      asm volatile("s_waitcnt vmcnt(8) lgkmcnt(0)" ::: "memory");
  else if (VM == 4) asm volatile("s_waitcnt vmcnt(4) lgkmcnt(0)" ::: "memory");
  else if (VM == 0) asm volatile("s_waitcnt vmcnt(0) lgkmcnt(0)" ::: "memory");
  else              asm volatile("s_waitcnt lgkmcnt(0)" ::: "memory");
  __builtin_amdgcn_s_barrier();
  __builtin_amdgcn_s_setprio(1);
#pragma unroll
  for (int mi = 0; mi < 4; mi++)
#pragma unroll
    for (int ni = 0; ni < 4; ni++)
      acc[mi + 4][ni] = MFMA(a[mi], b[ni], acc[mi + 4][ni]);
  __builtin_amdgcn_s_setprio(0);
  __builtin_amdgcn_s_barrier();
}

// EPI=0: H = gelu(A@B + bias), bf16. EPI=1: O = resid + A@B + bias, f32.
template <int EPI, int LDA, int LDC, int KTOT>
__global__ __launch_bounds__(512, 2) void gemm256(const ushort_t* __restrict__ A,
                                                  const ushort_t* __restrict__ Bw,
                                                  const float* __restrict__ bias,
                                                  const float* __restrict__ resid,
                                                  ushort_t* __restrict__ Hout,
                                                  float* __restrict__ Fout) {
  extern __shared__ char smem[];
  const int tid = threadIdx.x;
  const int wave = tid >> 6, lane = tid & 63;

  // XCD-aware bijective swizzle; per XCD: 8 m-tiles x (grid/64) n-tiles
  const int bid = blockIdx.x;
  const int c = bid & 7, l = bid >> 3;
  const int tm = c * 8 + (l & 7);
  const int tn = l >> 3;
  const int row0 = tm * 256;
  const int col0 = tn * 256;
  const int e = (row0 >> 9) & 7;

  const ushort_t* gA = A + (size_t)row0 * LDA;
  const ushort_t* gB = Bw + ((size_t)e * LDC + col0) * LDA;

  const int NT = KTOT / 32;

  // fragment read offsets (swizzled): s = g ^ ((r>>1)&3)
  const int wm = wave >> 2, wn = wave & 3;
  const int l15 = lane & 15, g = lane >> 4;
  const int sw = ((g ^ ((lane >> 1) & 3)) << 4);
  const int a_off = wm * 8192 + l15 * 64 + sw;
  const int b_off = 16384 + (wn >> 1) * 8192 + (wn & 1) * 4096 + l15 * 64 + sw;

  f32x4 acc[8][4] = {};

  // prologue: stage tiles 0,1,2 (A0,A1,B0,B1 each)
#pragma unroll
  for (int T = 0; T < 3; ++T) {
    char* s = smem + T * SLOT;
    stage_half(gA, LDA, s, T * 32, tid);
    stage_half(gA + (size_t)128 * LDA, LDA, s + 8192, T * 32, tid);
    stage_half(gB, LDA, s + 16384, T * 32, tid);
    stage_half(gB + (size_t)128 * LDA, LDA, s + 24576, T * 32, tid);
  }
  asm volatile("s_waitcnt vmcnt(8)" ::: "memory");   // tile 0 landed
  __builtin_amdgcn_s_barrier();

#pragma unroll 4
  for (int T = 0; T < NT - 3; ++T)
    tile_body<8, true>(smem, T, gA, gB, LDA, a_off, b_off, tid, acc);
  tile_body<4, false>(smem, NT - 3, gA, gB, LDA, a_off, b_off, tid, acc);
  tile_body<0, false>(smem, NT - 2, gA, gB, LDA, a_off, b_off, tid, acc);
  tile_body<-1, false>(smem, NT - 1, gA, gB, LDA, a_off, b_off, tid, acc);

  // ---------------- epilogue ----------------
  const int rbase = row0 + wm * 128 + g * 4;
  const int cbase = col0 + wn * 64 + l15;
  const float* bp = bias + e * LDC;
#pragma unroll
  for (int ni = 0; ni < 4; ni++) {
    const int n = cbase + ni * 16;
    const float bv = bp[n];
#pragma unroll
    for (int mi = 0; mi < 8; mi++) {
#pragma unroll
      for (int r = 0; r < 4; r++) {
        const int row = rbase + mi * 16 + r;
        float v = acc[mi][ni][r] + bv;
        if (EPI == 0) {
          float v2 = v * v;
          float cc = fmaf(0.044715f, v2, 1.0f);
          float xa = -2.3022078f * v * cc;          // -2*k*log2(e)*v*cc
          float u  = exp2f(xa);
          float o  = __fdividef(v, 1.0f + u);
          Hout[(size_t)row * LDC + n] = (ushort_t)f2bf(o);
        } else {
          const size_t idx = (size_t)row * LDC + n;
          Fout[idx] = resid[idx] + v;
        }
      }
    }
  }
}

extern "C" void kernel_launch(void* const* d_in, const int* in_sizes, int n_in,
                              void* d_out, int out_size, void* d_ws, size_t ws_size,
                              hipStream_t stream) {
  const float* x     = (const float*)d_in[0];
  const float* gamma = (const float*)d_in[1];
  const float* beta  = (const float*)d_in[2];
  // d_in[3] = gate_w : logits discarded by the reference -> skip
  const float* w1    = (const float*)d_in[4];
  const float* b1    = (const float*)d_in[5];
  const float* w2    = (const float*)d_in[6];
  const float* b2    = (const float*)d_in[7];
  float* out = (float*)d_out;

  char* ws = (char*)d_ws;
  ushort_t* xn  = (ushort_t*)ws;                                   // 32MB
  ushort_t* w1t = (ushort_t*)(ws + 33554432);                      // 64MB
  ushort_t* w2t = (ushort_t*)(ws + 33554432 + 67108864);           // 64MB
  ushort_t* h   = (ushort_t*)(ws + 33554432 + 2 * 67108864);       // 128MB

  hipFuncSetAttribute(reinterpret_cast<const void*>(&gemm256<0, 1024, 4096, 1024>),
                      hipFuncAttributeMaxDynamicSharedMemorySize, 131072);
  hipFuncSetAttribute(reinterpret_cast<const void*>(&gemm256<1, 4096, 1024, 4096>),
                      hipFuncAttributeMaxDynamicSharedMemorySize, 131072);

  ln_kernel<<<16384, 256, 0, stream>>>(x, gamma, beta, xn);
  transpose_cast<<<dim3(128, 32, 8), dim3(32, 8), 0, stream>>>(w1, w1t, 1024, 4096);
  transpose_cast<<<dim3(32, 128, 8), dim3(32, 8), 0, stream>>>(w2, w2t, 4096, 1024);

  // GEMM1: M=16384 N=4096 K=1024 -> h = gelu(xn@w1 + b1)
  gemm256<0, 1024, 4096, 1024><<<dim3(1024), 512, 131072, stream>>>(xn, w1t, b1, nullptr, h, nullptr);
  // GEMM2: M=16384 N=1024 K=4096 -> out = x + h@w2 + b2
  gemm256<1, 4096, 1024, 4096><<<dim3(256), 512, 131072, stream>>>(h, w2t, b2, x, nullptr, out);
}

// Round 4
// 424.018 us; speedup vs baseline: 1.3521x; 1.0937x over previous
//
#include <hip/hip_runtime.h>
#include <stdint.h>
#include <math.h>

typedef unsigned short ushort_t;
typedef __attribute__((ext_vector_type(8))) short bf16x8;
typedef __attribute__((ext_vector_type(4))) float f32x4;

#define SLOT 32768
#define EPI_STRIDE 1032   // 258 f32 per LDS row (conflict-free epilogue)

__device__ __forceinline__ ushort_t f2bf(float f) {
  union { float f; unsigned u; } cv; cv.f = f;
  unsigned r = cv.u + 0x7fffu + ((cv.u >> 16) & 1u);
  return (ushort_t)(r >> 16);
}

__device__ __forceinline__ void gl_lds16(const void* g, void* l) {
  typedef __attribute__((address_space(1))) const char gchar;
  typedef __attribute__((address_space(3))) char lchar;
  __builtin_amdgcn_global_load_lds((gchar*)g, (lchar*)l, 16, 0, 0);
}

__device__ __forceinline__ f32x4 MFMA(bf16x8 a, bf16x8 b, f32x4 c) {
  return __builtin_amdgcn_mfma_f32_16x16x32_bf16(a, b, c, 0, 0, 0);
}

// ---------------- LayerNorm (fp32 in) -> bf16 xn ----------------
__global__ __launch_bounds__(256) void ln_kernel(const float* __restrict__ x,
                                                 const float* __restrict__ gamma,
                                                 const float* __restrict__ beta,
                                                 ushort_t* __restrict__ xn) {
  const int row = blockIdx.x;
  const int t = threadIdx.x;
  const float4 v = ((const float4*)(x + (size_t)row * 1024))[t];
  float s  = v.x + v.y + v.z + v.w;
  float ss = v.x * v.x + v.y * v.y + v.z * v.z + v.w * v.w;
#pragma unroll
  for (int o = 32; o >= 1; o >>= 1) {
    s  += __shfl_xor(s, o);
    ss += __shfl_xor(ss, o);
  }
  __shared__ float red[10];
  const int wave = t >> 6, lane = t & 63;
  if (lane == 0) { red[wave] = s; red[4 + wave] = ss; }
  __syncthreads();
  if (t == 0) {
    float S  = red[0] + red[1] + red[2] + red[3];
    float SS = red[4] + red[5] + red[6] + red[7];
    float mu  = S * (1.0f / 1024.0f);
    float var = SS * (1.0f / 1024.0f) - mu * mu;
    red[8] = mu;
    red[9] = rsqrtf(var + 1e-5f);
  }
  __syncthreads();
  const float mu = red[8], rs = red[9];
  const float4 g = ((const float4*)gamma)[t];
  const float4 b = ((const float4*)beta)[t];
  ushort4 o;
  o.x = f2bf((v.x - mu) * rs * g.x + b.x);
  o.y = f2bf((v.y - mu) * rs * g.y + b.y);
  o.z = f2bf((v.z - mu) * rs * g.z + b.z);
  o.w = f2bf((v.w - mu) * rs * g.w + b.w);
  ((ushort4*)(xn + (size_t)row * 1024))[t] = o;
}

// ---------------- transpose + cast: in[e][R][C] fp32 -> out[e][C][R] bf16 ----------------
__global__ __launch_bounds__(256) void transpose_cast(const float* __restrict__ in,
                                                      ushort_t* __restrict__ out,
                                                      int R, int C) {
  __shared__ float tile[32][33];
  const int e = blockIdx.z;
  const float* src = in + (size_t)e * R * C;
  ushort_t* dst = out + (size_t)e * R * C;
  const int c0 = blockIdx.x * 32, r0 = blockIdx.y * 32;
  const int tx = threadIdx.x, ty = threadIdx.y;
#pragma unroll
  for (int j = 0; j < 32; j += 8)
    tile[ty + j][tx] = src[(size_t)(r0 + ty + j) * C + c0 + tx];
  __syncthreads();
#pragma unroll
  for (int j = 0; j < 32; j += 8)
    dst[(size_t)(c0 + ty + j) * R + r0 + tx] = f2bf(tile[tx][ty + j]);
}

// ======== 256x256 / BK=32 / ring-4, register-double-buffered 2-phase GEMM ========
// Slot (32KB): A-h0 @0, A-h1 @8192, B-h0 @16384, B-h1 @24576. Rows = 64B.
// Swizzle: global granule g of row r lives at LDS granule g ^ ((r>>1)&3).

__device__ __forceinline__ void stage_half(const ushort_t* gsrc, int lda,
                                           char* half_base, int kt, int tid) {
  const int rr = tid >> 2;
  const int gs = (tid & 3) ^ ((tid >> 3) & 3);
  gl_lds16(gsrc + (size_t)rr * lda + kt + gs * 8, half_base + (tid >> 6) * 1024);
}

template <int BASE>
__device__ __forceinline__ void mfma16(const bf16x8 (&a)[4], const bf16x8 (&b)[4],
                                       f32x4 (&acc)[8][4]) {
  __builtin_amdgcn_s_setprio(1);
#pragma unroll
  for (int mi = 0; mi < 4; mi++)
#pragma unroll
    for (int ni = 0; ni < 4; ni++)
      acc[BASE + mi][ni] = MFMA(a[mi], b[ni], acc[BASE + mi][ni]);
  __builtin_amdgcn_s_setprio(0);
}

// Phase A consumes (bA0, bBc) -> acc[0..3]; prefetches A_T[4..7] -> bA1.
// Phase B consumes (bA1, bBc) -> acc[4..7]; prefetches slot T+1 -> (bA0, bBn).
template <int VM, bool STG, bool LAST>
__device__ __forceinline__ void tile_body(char* smem, int T,
                                          const ushort_t* gA, const ushort_t* gB,
                                          int lda, int a_off, int b_off, int tid,
                                          bf16x8 (&bA0)[4], bf16x8 (&bA1)[4],
                                          bf16x8 (&bBc)[4], bf16x8 (&bBn)[4],
                                          f32x4 (&acc)[8][4]) {
  const char* slot = smem + (T & 3) * SLOT;
  char* nstg = smem + ((T + 3) & 3) * SLOT;
  const int kt3 = (T + 3) * 32;
  // ---- phase A ----
#pragma unroll
  for (int mi = 0; mi < 4; mi++) bA1[mi] = *(const bf16x8*)(slot + a_off + (mi + 4) * 1024);
  if (STG) {
    stage_half(gA, lda, nstg, kt3, tid);
    stage_half(gA + (size_t)128 * lda, lda, nstg + 8192, kt3, tid);
  }
  __builtin_amdgcn_sched_barrier(0);
  __builtin_amdgcn_s_barrier();
  __builtin_amdgcn_sched_barrier(0);
  mfma16<0>(bA0, bBc, acc);
  __builtin_amdgcn_s_barrier();
  // ---- phase B ----
  if (VM == 6)      asm volatile("s_waitcnt vmcnt(6)" ::: "memory");
  else if (VM == 4) asm volatile("s_waitcnt vmcnt(4)" ::: "memory");
  else if (VM == 0) asm volatile("s_waitcnt vmcnt(0)" ::: "memory");
  __builtin_amdgcn_s_barrier();
  if (!LAST) {
    const char* nslot = smem + ((T + 1) & 3) * SLOT;
#pragma unroll
    for (int ni = 0; ni < 4; ni++) bBn[ni] = *(const bf16x8*)(nslot + b_off + ni * 1024);
#pragma unroll
    for (int mi = 0; mi < 4; mi++) bA0[mi] = *(const bf16x8*)(nslot + a_off + mi * 1024);
    if (STG) {
      stage_half(gB, lda, nstg + 16384, kt3, tid);
      stage_half(gB + (size_t)128 * lda, lda, nstg + 24576, kt3, tid);
    }
  }
  __builtin_amdgcn_sched_barrier(0);
  mfma16<4>(bA1, bBc, acc);
  __builtin_amdgcn_s_barrier();
}

// EPI=0: H = gelu(A@B + bias), bf16. EPI=1: O = resid + A@B + bias, f32.
template <int EPI, int LDA, int LDC, int KTOT>
__global__ __launch_bounds__(512, 2) void gemm256(const ushort_t* __restrict__ A,
                                                  const ushort_t* __restrict__ Bw,
                                                  const float* __restrict__ bias,
                                                  const float* __restrict__ resid,
                                                  ushort_t* __restrict__ Hout,
                                                  float* __restrict__ Fout) {
  extern __shared__ char smem[];
  const int tid = threadIdx.x;
  const int wave = tid >> 6, lane = tid & 63;

  const int bid = blockIdx.x;
  const int c = bid & 7, l = bid >> 3;
  const int tm = c * 8 + (l & 7);
  const int tn = l >> 3;
  const int row0 = tm * 256;
  const int col0 = tn * 256;
  const int e = (row0 >> 9) & 7;

  const ushort_t* gA = A + (size_t)row0 * LDA;
  const ushort_t* gB = Bw + ((size_t)e * LDC + col0) * LDA;

  const int NT = KTOT / 32;

  const int wm = wave >> 2, wn = wave & 3;
  const int l15 = lane & 15, g = lane >> 4;
  const int sw = ((g ^ ((lane >> 1) & 3)) << 4);
  const int a_off = wm * 8192 + l15 * 64 + sw;
  const int b_off = 16384 + (wn >> 1) * 8192 + (wn & 1) * 4096 + l15 * 64 + sw;

  f32x4 acc[8][4] = {};
  bf16x8 bA0[4], bA1[4], bB0[4], bB1[4];

  // prologue: stage tiles 0,1,2
#pragma unroll
  for (int T = 0; T < 3; ++T) {
    char* s = smem + T * SLOT;
    stage_half(gA, LDA, s, T * 32, tid);
    stage_half(gA + (size_t)128 * LDA, LDA, s + 8192, T * 32, tid);
    stage_half(gB, LDA, s + 16384, T * 32, tid);
    stage_half(gB + (size_t)128 * LDA, LDA, s + 24576, T * 32, tid);
  }
  asm volatile("s_waitcnt vmcnt(8)" ::: "memory");   // tile 0 landed
  __builtin_amdgcn_s_barrier();
#pragma unroll
  for (int ni = 0; ni < 4; ni++) bB0[ni] = *(const bf16x8*)(smem + b_off + ni * 1024);
#pragma unroll
  for (int mi = 0; mi < 4; mi++) bA0[mi] = *(const bf16x8*)(smem + a_off + mi * 1024);

  for (int T = 0; T < NT - 4; T += 2) {
    tile_body<6, true, false>(smem, T,     gA, gB, LDA, a_off, b_off, tid, bA0, bA1, bB0, bB1, acc);
    tile_body<6, true, false>(smem, T + 1, gA, gB, LDA, a_off, b_off, tid, bA0, bA1, bB1, bB0, acc);
  }
  tile_body<6, true,  false>(smem, NT - 4, gA, gB, LDA, a_off, b_off, tid, bA0, bA1, bB0, bB1, acc);
  tile_body<4, false, false>(smem, NT - 3, gA, gB, LDA, a_off, b_off, tid, bA0, bA1, bB1, bB0, acc);
  tile_body<0, false, false>(smem, NT - 2, gA, gB, LDA, a_off, b_off, tid, bA0, bA1, bB0, bB1, acc);
  tile_body<-1, false, true>(smem, NT - 1, gA, gB, LDA, a_off, b_off, tid, bA0, bA1, bB1, bB0, acc);

  // ---------------- LDS-gather epilogue: 4 rounds x 64 rows ----------------
  __syncthreads();   // drain all LDS reads before reuse

  float bv[4];
#pragma unroll
  for (int ni = 0; ni < 4; ni++)
    bv[ni] = bias[e * LDC + col0 + wn * 64 + ni * 16 + l15];

#pragma unroll
  for (int r = 0; r < 4; ++r) {
    // write side: frags mi = 2r, 2r+1 (rows wm*128 + [r*32, r*32+32))
#pragma unroll
    for (int mh = 0; mh < 2; ++mh) {
      const int mi = 2 * r + mh;
      const int lrow = wm * 32 + mh * 16 + g * 4;
#pragma unroll
      for (int ni = 0; ni < 4; ++ni) {
        const int colb = (wn * 64 + ni * 16 + l15) * 4;
#pragma unroll
        for (int rr = 0; rr < 4; ++rr) {
          float v = acc[mi][ni][rr] + bv[ni];
          if (EPI == 0) {
            float v2 = v * v;
            float cc = fmaf(0.044715f, v2, 1.0f);
            float u  = exp2f(-2.3022078f * v * cc);
            v = __fdividef(v, 1.0f + u);
          }
          *(float*)(smem + (size_t)(lrow + rr) * EPI_STRIDE + colb) = v;
        }
      }
    }
    __syncthreads();
    // read side: 64 rows x 256 cols, coalesced wide stores
#pragma unroll
    for (int i = 0; i < 8; ++i) {
      const int chunk = i * 512 + tid;
      const int lr = chunk >> 6;
      const int cb = (chunk & 63) * 16;
      const float4 v4 = *(const float4*)(smem + (size_t)lr * EPI_STRIDE + cb);
      const int grow = row0 + (lr < 32 ? r * 32 + lr : 128 + r * 32 + (lr - 32));
      const int gcol = col0 + (chunk & 63) * 4;
      if (EPI == 0) {
        ushort4 o;
        o.x = f2bf(v4.x); o.y = f2bf(v4.y); o.z = f2bf(v4.z); o.w = f2bf(v4.w);
        *(ushort4*)(&Hout[(size_t)grow * LDC + gcol]) = o;
      } else {
        const float4 rs = *(const float4*)(&resid[(size_t)grow * LDC + gcol]);
        float4 o;
        o.x = v4.x + rs.x; o.y = v4.y + rs.y; o.z = v4.z + rs.z; o.w = v4.w + rs.w;
        *(float4*)(&Fout[(size_t)grow * LDC + gcol]) = o;
      }
    }
    __syncthreads();
  }
}

extern "C" void kernel_launch(void* const* d_in, const int* in_sizes, int n_in,
                              void* d_out, int out_size, void* d_ws, size_t ws_size,
                              hipStream_t stream) {
  const float* x     = (const float*)d_in[0];
  const float* gamma = (const float*)d_in[1];
  const float* beta  = (const float*)d_in[2];
  // d_in[3] = gate_w : logits discarded by the reference -> skip
  const float* w1    = (const float*)d_in[4];
  const float* b1    = (const float*)d_in[5];
  const float* w2    = (const float*)d_in[6];
  const float* b2    = (const float*)d_in[7];
  float* out = (float*)d_out;

  char* ws = (char*)d_ws;
  ushort_t* xn  = (ushort_t*)ws;                                   // 32MB
  ushort_t* w1t = (ushort_t*)(ws + 33554432);                      // 64MB
  ushort_t* w2t = (ushort_t*)(ws + 33554432 + 67108864);           // 64MB
  ushort_t* h   = (ushort_t*)(ws + 33554432 + 2 * 67108864);       // 128MB

  hipFuncSetAttribute(reinterpret_cast<const void*>(&gemm256<0, 1024, 4096, 1024>),
                      hipFuncAttributeMaxDynamicSharedMemorySize, 131072);
  hipFuncSetAttribute(reinterpret_cast<const void*>(&gemm256<1, 4096, 1024, 4096>),
                      hipFuncAttributeMaxDynamicSharedMemorySize, 131072);

  ln_kernel<<<16384, 256, 0, stream>>>(x, gamma, beta, xn);
  transpose_cast<<<dim3(128, 32, 8), dim3(32, 8), 0, stream>>>(w1, w1t, 1024, 4096);
  transpose_cast<<<dim3(32, 128, 8), dim3(32, 8), 0, stream>>>(w2, w2t, 4096, 1024);

  // GEMM1: M=16384 N=4096 K=1024 -> h = gelu(xn@w1 + b1)
  gemm256<0, 1024, 4096, 1024><<<dim3(1024), 512, 131072, stream>>>(xn, w1t, b1, nullptr, h, nullptr);
  // GEMM2: M=16384 N=1024 K=4096 -> out = x + h@w2 + b2
  gemm256<1, 4096, 1024, 4096><<<dim3(256), 512, 131072, stream>>>(h, w2t, b2, x, nullptr, out);
}